// Round 11
// baseline (177.656 us; speedup 1.0000x reference)
//
#include <hip/hip_runtime.h>

// GCN layer: out = relu(x @ W_self^T + b_self + segment_mean(x[src], dst) @ W_neigh^T)
// N = 100000 nodes, D = 64, E = 1.25M edges.
//
// R3 structure: mean-then-matmul == matmul-then-mean (linearity).
// y = x@Ws^T + b and z = x@Wn^T computed FIRST (bf16 planes); gather averages
// z rows and finishes out = relu(y + mean).
// R4 lesson: per-edge scattered 4B global writes = 16x write amplification.
// R6 lesson: __shfl with divergent-exit loops is UB on gfx950.
// R10 lesson: claim-storm theory FALSIFIED (count-only+GEMM still ~44 µs).
//   Every front-kernel variant pins at 44-50 µs; sb_csr and gather are also
//   ~40 µs-class; totals track DISPATCH COUNT (~25-40 µs/dispatch floor across
//   R1/R7/R10) better than kernel contents. => minimize dispatches.
//
// R11: 3 dispatches (memset + 2 kernels):
//   memset    : cursor[256] = 0.
//   k1_main   : blocks [0,SCB): LDS-staged radix scatter into 196 buckets of
//               512 dst-nodes (contiguous-run claim via cursor atomics —
//               proven innocent in R10 — full-line ebuf writes).
//               Blocks [SCB,+GB): dual MFMA GEMM from fp32 x -> bf16 y,z.
//   sb_gather : FUSED sb_csr + gather. One 1024-thread block per bucket:
//               window staged to regs, in-LDS node-sort (LDS *int* atomics
//               only — fp32 LDS atomicAdd is a CAS-loop disaster), then the
//               SAME block gathers for its 512 nodes straight from the
//               LDS-sorted adjacency (16 waves, 32 nodes/wave). Deletes the
//               col/rowse planes (~15 MB round trip) and one dispatch.
//               Adjacency indices via LDS reads -> any degree handled by one
//               uniform loop (no deg<=64 shfl window restriction).

#define BKSH 9                // log2(nodes per bucket)
#define BKN 512               // nodes per bucket
#define NBMAX 256             // >= NB = 196
#define CAPE 7168             // edge capacity per bucket (mean 6400, +9.6 sigma)
#define CHUNK 4096            // edges per scatter block
#define EPT (CHUNK / 256)     // edges per thread in scatter = 16
#define WPT2 (CAPE / 1024)    // window entries per thread in sb_gather = 7

typedef __attribute__((ext_vector_type(8))) short short8;
typedef __attribute__((ext_vector_type(4))) float floatx4;

// fp32 -> bf16 round-to-nearest-even, branch-free.
static __device__ inline unsigned short f2bf(float f) {
  union { float f; unsigned int u; } v;
  v.f = f;
  unsigned int r = v.u + 0x7FFFu + ((v.u >> 16) & 1u);
  return (unsigned short)(r >> 16);
}

static __device__ inline short8 pack8(float4 a, float4 b) {
  short8 s;
  s[0] = (short)f2bf(a.x); s[1] = (short)f2bf(a.y);
  s[2] = (short)f2bf(a.z); s[3] = (short)f2bf(a.w);
  s[4] = (short)f2bf(b.x); s[5] = (short)f2bf(b.y);
  s[6] = (short)f2bf(b.z); s[7] = (short)f2bf(b.w);
  return s;
}

// unpack 8 bf16 (4 dwords) and accumulate into 8 fp32.
static __device__ inline void add8(float* a, short8 sv) {
  union { short8 s; unsigned int u[4]; } c; c.s = sv;
#pragma unroll
  for (int i = 0; i < 4; ++i) {
    a[2 * i]     += __uint_as_float(c.u[i] << 16);
    a[2 * i + 1] += __uint_as_float(c.u[i] & 0xFFFF0000u);
  }
}

// unpack 8 bf16 into 8 fp32 (no accumulate).
static __device__ inline void cvt8(float* a, short8 sv) {
  union { short8 s; unsigned int u[4]; } c; c.s = sv;
#pragma unroll
  for (int i = 0; i < 4; ++i) {
    a[2 * i]     = __uint_as_float(c.u[i] << 16);
    a[2 * i + 1] = __uint_as_float(c.u[i] & 0xFFFF0000u);
  }
}

// Fused: edge radix-scatter (blocks < SCB) | dual-GEMM y,z from fp32 x.
__global__ __launch_bounds__(256) void k1_main(
    const float* __restrict__ x,
    const float* __restrict__ Wself, const float* __restrict__ bself,
    const float* __restrict__ Wneigh,
    unsigned short* __restrict__ yb, unsigned short* __restrict__ zb,
    const int* __restrict__ src, const int* __restrict__ dst,
    int* __restrict__ cursor, int* __restrict__ ebuf,
    int E, int N, int NB, int SCB) {
  __shared__ int h[NBMAX], loff[NBMAX], gbase[NBMAX];
  __shared__ int sbuf[CHUNK];
  int t = threadIdx.x;
  int bid = blockIdx.x;

  if (bid >= SCB) {
    // ---- GEMM role: y = x@Ws^T + b (bf16), z = x@Wn^T (bf16) ----
    int lane = t & 63;
    int w = t >> 6;
    int tb = (bid - SCB) * 64 + w * 16;
    int m = lane & 15, q = lane >> 4;

    long long rowA = (long long)min(tb + m, N - 1) * 64;
    short8 ax[2];
#pragma unroll
    for (int ks = 0; ks < 2; ++ks) {
      const float* xr = &x[rowA + ks * 32 + q * 8];
      ax[ks] = pack8(*(const float4*)xr, *(const float4*)(xr + 4));
    }

#pragma unroll
    for (int nt = 0; nt < 4; ++nt) {
      int ob = nt * 16;
      long long rowB = (long long)(ob + m) * 64;
      floatx4 accs = {0.f, 0.f, 0.f, 0.f};
      floatx4 accn = {0.f, 0.f, 0.f, 0.f};
#pragma unroll
      for (int ks = 0; ks < 2; ++ks) {
        const float* pw = &Wself[rowB + ks * 32 + q * 8];
        short8 bs = pack8(*(const float4*)pw, *(const float4*)(pw + 4));
        accs = __builtin_amdgcn_mfma_f32_16x16x32_bf16(ax[ks], bs, accs, 0, 0, 0);
        const float* pn = &Wneigh[rowB + ks * 32 + q * 8];
        short8 bn = pack8(*(const float4*)pn, *(const float4*)(pn + 4));
        accn = __builtin_amdgcn_mfma_f32_16x16x32_bf16(ax[ks], bn, accn, 0, 0, 0);
      }
      float bias = bself[ob + m];
#pragma unroll
      for (int r = 0; r < 4; ++r) {
        int node = tb + q * 4 + r;
        if (node < N) {
          yb[(long long)node * 64 + ob + m] = f2bf(accs[r] + bias);
          zb[(long long)node * 64 + ob + m] = f2bf(accn[r]);
        }
      }
    }
    return;
  }

  // ---- scatter role ----
  int w = t >> 6, lane = t & 63;
  if (t < NBMAX) h[t] = 0;
  __syncthreads();

  int base = bid * CHUNK;
  int myd[EPT], mys[EPT];
#pragma unroll
  for (int i = 0; i < EPT; ++i) {
    int e = base + t + 256 * i;  // coalesced
    if (e < E) {
      myd[i] = dst[e];
      mys[i] = src[e];
      atomicAdd(&h[myd[i] >> BKSH], 1);
    } else myd[i] = -1;
  }
  __syncthreads();

  if (t < 64) {  // wave 0: exclusive scan of h[0..255], 4 per lane
    int i0 = 4 * t;
    int v0 = h[i0], v1 = h[i0 + 1], v2 = h[i0 + 2], v3 = h[i0 + 3];
    int s4 = v0 + v1 + v2 + v3, inc = s4;
#pragma unroll
    for (int off = 1; off < 64; off <<= 1) {
      int u = __shfl_up(inc, off, 64);
      if (t >= off) inc += u;
    }
    int ex = inc - s4;
    loff[i0] = ex; loff[i0 + 1] = ex + v0;
    loff[i0 + 2] = ex + v0 + v1; loff[i0 + 3] = ex + v0 + v1 + v2;
  }
  __syncthreads();

  if (t < NB) {
    if (h[t] > 0) gbase[t] = t * CAPE + atomicAdd(&cursor[t], h[t]);  // claim
  }
  __syncthreads();
  if (t < NBMAX) h[t] = 0;  // reuse as local cursor
  __syncthreads();

#pragma unroll
  for (int i = 0; i < EPT; ++i) {
    if (myd[i] >= 0) {
      int b = myd[i] >> BKSH;
      int p = atomicAdd(&h[b], 1);           // LDS int atomic: native, fast
      sbuf[loff[b] + p] = mys[i] | ((myd[i] & (BKN - 1)) << 17);  // src < 2^17
    }
  }
  __syncthreads();

  for (int b = w; b < NB; b += 4) {
    int c = h[b], lo = loff[b], go = gbase[b];
    for (int j = lane; j < c; j += 64)
      ebuf[go + j] = sbuf[lo + j];
  }
}

// FUSED sort+gather: one 1024-thread block per 512-node bucket (196 blocks).
// Phase 1 (sort): window staged to registers, count -> block scan -> in-LDS
// node-sort. off[nl]=start, cnt[nl]=end (relative, within this bucket).
// Phase 2 (gather): wave w (of 16) handles nodes nl = w*32..w*32+31. Adjacency
// indices read straight from LDS sbuf (same-address across octs = broadcast),
// 2 z-loads in flight, wave-uniform trip count (c is wave-uniform: whole wave
// works one node), cross-oct shfl reduce, epilogue out = relu(y + mean).
__global__ __launch_bounds__(1024) void sb_gather(
    const int* __restrict__ cursor,
    const int* __restrict__ ebuf,
    const unsigned short* __restrict__ zb,
    const unsigned short* __restrict__ yb,
    float* __restrict__ out, int N) {
  __shared__ int sbuf[CAPE];   // 28672 B
  __shared__ int cnt[BKN];     //  2048 B (seeded start -> becomes end)
  __shared__ int off[BKN];     //  2048 B (start)
  __shared__ int wsum[8];      // total ~32.8 KB
  int b = blockIdx.x, t = threadIdx.x;
  int s = b * CAPE;
  int n = cursor[b];
  int e = s + n;

  // ---- phase 1: stage + count + scan + sort ----
  int my[WPT2];
#pragma unroll
  for (int i = 0; i < WPT2; ++i) {
    int j = s + t + (i << 10);
    my[i] = (j < e) ? ebuf[j] : -1;  // entries < 2^26, -1 safe sentinel
  }
  if (t < BKN) cnt[t] = 0;
  __syncthreads();
#pragma unroll
  for (int i = 0; i < WPT2; ++i)
    if (my[i] >= 0) atomicAdd(&cnt[(my[i] >> 17) & (BKN - 1)], 1);
  __syncthreads();

  // block exclusive scan over 512 (threads 0..511 = waves 0..7, whole waves)
  int v = 0, inc = 0;
  int lane = t & 63, w = t >> 6;
  if (t < BKN) {
    v = cnt[t];
    inc = v;
#pragma unroll
    for (int o = 1; o < 64; o <<= 1) {
      int u = __shfl_up(inc, o, 64);
      if (lane >= o) inc += u;
    }
    if (lane == 63) wsum[w] = inc;
  }
  __syncthreads();
  if (t < 8) {
    int s0 = wsum[t], incw = s0;
#pragma unroll
    for (int o = 1; o < 8; o <<= 1) {
      int u = __shfl_up(incw, o, 64);
      if (t >= o) incw += u;
    }
    wsum[t] = incw - s0;
  }
  __syncthreads();
  if (t < BKN) {
    int ex = wsum[w] + inc - v;
    off[t] = ex;
    cnt[t] = ex;  // seed scatter cursor with exclusive prefix
  }
  __syncthreads();

  // in-LDS node-sort: atomic result is the final position in the window
#pragma unroll
  for (int i = 0; i < WPT2; ++i) {
    if (my[i] >= 0) {
      int nl = (my[i] >> 17) & (BKN - 1);
      int p = atomicAdd(&cnt[nl], 1);
      sbuf[p] = my[i] & 0x1FFFF;
    }
  }
  __syncthreads();
  // now off[nl] = start, cnt[nl] = end (relative)

  // ---- phase 2: gather (no barriers below; per-wave independent) ----
  int o = lane >> 3, d = lane & 7;
  int nl0 = w * 32;
  for (int nl = nl0; nl < nl0 + 32; ++nl) {
    int node = (b << BKSH) + nl;
    if (node >= N) break;  // wave-uniform
    int s0 = off[nl];      // same address across lanes -> broadcast
    int c = cnt[nl] - s0;

    long long ro = (long long)node * 64 + d * 8;
    short8 yv8;
    if (o == 0) yv8 = *(const short8*)&yb[ro];  // prefetch, independent

    float a[8] = {0.f, 0.f, 0.f, 0.f, 0.f, 0.f, 0.f, 0.f};
    float b2[8] = {0.f, 0.f, 0.f, 0.f, 0.f, 0.f, 0.f, 0.f};
    for (int kb = 0; kb < c; kb += 16) {  // c wave-uniform; any degree
      int k0 = kb + o, k1 = k0 + 8;
      bool p0 = k0 < c, p1 = k1 < c;
      int c0 = sbuf[s0 + (p0 ? k0 : 0)];  // LDS: 8 octs -> 8 addrs, broadcast in oct
      int c1 = sbuf[s0 + (p1 ? k1 : 0)];
      short8 v0 = *(const short8*)&zb[(long long)c0 * 64 + d * 8];
      short8 v1 = *(const short8*)&zb[(long long)c1 * 64 + d * 8];
      if (p0) add8(a, v0);
      if (p1) add8(b2, v1);
    }
#pragma unroll
    for (int k = 0; k < 8; ++k) a[k] += b2[k];

#pragma unroll
    for (int m = 8; m <= 32; m <<= 1) {
#pragma unroll
      for (int k = 0; k < 8; ++k) a[k] += __shfl_xor(a[k], m, 64);
    }

    if (o == 0) {
      float inv = 1.0f / fmaxf((float)c, 1.0f);
      float yv[8];
      cvt8(yv, yv8);
      float4 r0, r1;
      r0.x = fmaxf(yv[0] + a[0] * inv, 0.f);
      r0.y = fmaxf(yv[1] + a[1] * inv, 0.f);
      r0.z = fmaxf(yv[2] + a[2] * inv, 0.f);
      r0.w = fmaxf(yv[3] + a[3] * inv, 0.f);
      r1.x = fmaxf(yv[4] + a[4] * inv, 0.f);
      r1.y = fmaxf(yv[5] + a[5] * inv, 0.f);
      r1.z = fmaxf(yv[6] + a[6] * inv, 0.f);
      r1.w = fmaxf(yv[7] + a[7] * inv, 0.f);
      *(float4*)&out[ro] = r0;
      *(float4*)&out[ro + 4] = r1;
    }
  }
}

extern "C" void kernel_launch(void* const* d_in, const int* in_sizes, int n_in,
                              void* d_out, int out_size, void* d_ws, size_t ws_size,
                              hipStream_t stream) {
  const float* x      = (const float*)d_in[0];
  const int*   eidx   = (const int*)d_in[1];
  const float* Wself  = (const float*)d_in[2];
  const float* bself  = (const float*)d_in[3];
  const float* Wneigh = (const float*)d_in[4];
  float* out = (float*)d_out;

  const int N = in_sizes[0] / 64;
  const int E = in_sizes[1] / 2;
  const int* src = eidx;      // edge_index row 0
  const int* dst = eidx + E;  // edge_index row 1
  const int NB = (N + BKN - 1) / BKN;       // 196 buckets of 512 nodes
  const int SCB = (E + CHUNK - 1) / CHUNK;  // 306 scatter blocks

  // ws layout: yb bf16[N*64] | zb bf16[N*64] | cursor[256] | ebuf[NB*CAPE]
  //            (~31 MB; col/rowse planes deleted)
  unsigned short* yb = (unsigned short*)d_ws;
  unsigned short* zb = yb + (size_t)N * 64;
  int* cursor = (int*)(zb + (size_t)N * 64);
  int* ebuf   = cursor + NBMAX;

  hipMemsetAsync(cursor, 0, NBMAX * sizeof(int), stream);

  const int GB = (N + 63) / 64;  // 1563 GEMM blocks (64 nodes each)
  k1_main<<<SCB + GB, 256, 0, stream>>>(x, Wself, bself, Wneigh, yb, zb,
                                        src, dst, cursor, ebuf, E, N, NB, SCB);
  sb_gather<<<NB, 1024, 0, stream>>>(cursor, ebuf, zb, yb, out, N);
}

// Round 12
// 156.705 us; speedup vs baseline: 1.1337x; 1.1337x over previous
//
#include <hip/hip_runtime.h>

// GCN layer: out = relu(x @ W_self^T + b_self + segment_mean(x[src], dst) @ W_neigh^T)
// N = 100000 nodes, D = 64, E = 1.25M edges.
//
// R3 structure: mean-then-matmul == matmul-then-mean (linearity).
// y = x@Ws^T + b and z = x@Wn^T computed FIRST (bf16 planes); gather averages
// z rows and finishes out = relu(y + mean).
// R4 lesson: per-edge scattered 4B global writes = 16x write amplification.
// R6 lesson: __shfl with divergent-exit loops is UB on gfx950 — all shfl loops
//   use wave-uniform trip counts with predication.
// R10 lesson: cursor-claim-storm theory falsified (count-only+GEMM still 44 µs).
// R11 lesson: fusing sort+gather into 196 fat blocks capped TLP (1 blk/CU,
//   60 CUs idle) -> 63.5 µs vs split ~58. Latency-bound gather needs many
//   small blocks. Dispatch-count theory also falsified (3 disp = 177.7).
//   => revert to R7 pipeline (best: 158.6), optimize gather internals only.
//
// R12: oct-per-node gather. One oct (8 lanes) per node, 8 nodes per wave:
//   - lane owns 8 dims of its node across ALL edges -> ZERO cross-lane reduce
//     (was 24 shfl + 24 add per node) and all-64-lane epilogue writes
//     (8 contiguous 256B rows per wave, was 1/8 lanes active).
//   - inner loop: one 32B col-line fetch per oct per 8 edges, then 8
//     INDEPENDENT z-row loads (8-deep ILP, was 2-deep).
//   - loop bound = wave-max degree (uniform, shfl-safe); predicated-off lanes
//     load row 0 (L1-hot, harmless). Any degree handled.
//
// Pipeline (memset + 3 kernels):
//   memset      : cursor[256] = 0.
//   k1_main     : blocks [0,SCB): LDS-staged radix scatter into 196 buckets
//                 of 512 dst-nodes (contiguous-run claim, full-line ebuf
//                 writes). Blocks [SCB,+GB): dual MFMA GEMM -> bf16 y,z.
//                 UNTOUCHED from R7 (its 47 µs resisted 5 causal theories).
//   sb_csr      : one 512-thread block per bucket: window in registers,
//                 in-LDS node-sort, coalesced flush. LDS *int* atomics only
//                 (fp32 LDS atomicAdd = CAS-loop disaster).
//   gather_oct  : 3125 blocks x 256 thr, 32 nodes/block, oct-per-node.

#define BKSH 9                // log2(nodes per bucket)
#define BKN 512               // nodes per bucket
#define NBMAX 256             // >= NB = 196
#define CAPE 7168             // edge capacity per bucket (mean 6400, +9.6 sigma)
#define WPT (CAPE / BKN)      // window entries per thread in sb_csr = 14
#define CHUNK 4096            // edges per scatter block
#define EPT (CHUNK / 256)     // edges per thread in scatter = 16

typedef __attribute__((ext_vector_type(8))) short short8;
typedef __attribute__((ext_vector_type(4))) float floatx4;

// fp32 -> bf16 round-to-nearest-even, branch-free.
static __device__ inline unsigned short f2bf(float f) {
  union { float f; unsigned int u; } v;
  v.f = f;
  unsigned int r = v.u + 0x7FFFu + ((v.u >> 16) & 1u);
  return (unsigned short)(r >> 16);
}

static __device__ inline short8 pack8(float4 a, float4 b) {
  short8 s;
  s[0] = (short)f2bf(a.x); s[1] = (short)f2bf(a.y);
  s[2] = (short)f2bf(a.z); s[3] = (short)f2bf(a.w);
  s[4] = (short)f2bf(b.x); s[5] = (short)f2bf(b.y);
  s[6] = (short)f2bf(b.z); s[7] = (short)f2bf(b.w);
  return s;
}

// unpack 8 bf16 (4 dwords) and accumulate into 8 fp32.
static __device__ inline void add8(float* a, short8 sv) {
  union { short8 s; unsigned int u[4]; } c; c.s = sv;
#pragma unroll
  for (int i = 0; i < 4; ++i) {
    a[2 * i]     += __uint_as_float(c.u[i] << 16);
    a[2 * i + 1] += __uint_as_float(c.u[i] & 0xFFFF0000u);
  }
}

// unpack 8 bf16 into 8 fp32 (no accumulate).
static __device__ inline void cvt8(float* a, short8 sv) {
  union { short8 s; unsigned int u[4]; } c; c.s = sv;
#pragma unroll
  for (int i = 0; i < 4; ++i) {
    a[2 * i]     = __uint_as_float(c.u[i] << 16);
    a[2 * i + 1] = __uint_as_float(c.u[i] & 0xFFFF0000u);
  }
}

// Fused: edge radix-scatter (blocks < SCB) | dual-GEMM y,z from fp32 x.
__global__ __launch_bounds__(256) void k1_main(
    const float* __restrict__ x,
    const float* __restrict__ Wself, const float* __restrict__ bself,
    const float* __restrict__ Wneigh,
    unsigned short* __restrict__ yb, unsigned short* __restrict__ zb,
    const int* __restrict__ src, const int* __restrict__ dst,
    int* __restrict__ cursor, int* __restrict__ ebuf,
    int E, int N, int NB, int SCB) {
  __shared__ int h[NBMAX], loff[NBMAX], gbase[NBMAX];
  __shared__ int sbuf[CHUNK];
  int t = threadIdx.x;
  int bid = blockIdx.x;

  if (bid >= SCB) {
    // ---- GEMM role: y = x@Ws^T + b (bf16), z = x@Wn^T (bf16) ----
    int lane = t & 63;
    int w = t >> 6;
    int tb = (bid - SCB) * 64 + w * 16;
    int m = lane & 15, q = lane >> 4;

    long long rowA = (long long)min(tb + m, N - 1) * 64;
    short8 ax[2];
#pragma unroll
    for (int ks = 0; ks < 2; ++ks) {
      const float* xr = &x[rowA + ks * 32 + q * 8];
      ax[ks] = pack8(*(const float4*)xr, *(const float4*)(xr + 4));
    }

#pragma unroll
    for (int nt = 0; nt < 4; ++nt) {
      int ob = nt * 16;
      long long rowB = (long long)(ob + m) * 64;
      floatx4 accs = {0.f, 0.f, 0.f, 0.f};
      floatx4 accn = {0.f, 0.f, 0.f, 0.f};
#pragma unroll
      for (int ks = 0; ks < 2; ++ks) {
        const float* pw = &Wself[rowB + ks * 32 + q * 8];
        short8 bs = pack8(*(const float4*)pw, *(const float4*)(pw + 4));
        accs = __builtin_amdgcn_mfma_f32_16x16x32_bf16(ax[ks], bs, accs, 0, 0, 0);
        const float* pn = &Wneigh[rowB + ks * 32 + q * 8];
        short8 bn = pack8(*(const float4*)pn, *(const float4*)(pn + 4));
        accn = __builtin_amdgcn_mfma_f32_16x16x32_bf16(ax[ks], bn, accn, 0, 0, 0);
      }
      float bias = bself[ob + m];
#pragma unroll
      for (int r = 0; r < 4; ++r) {
        int node = tb + q * 4 + r;
        if (node < N) {
          yb[(long long)node * 64 + ob + m] = f2bf(accs[r] + bias);
          zb[(long long)node * 64 + ob + m] = f2bf(accn[r]);
        }
      }
    }
    return;
  }

  // ---- scatter role ----
  int w = t >> 6, lane = t & 63;
  if (t < NBMAX) h[t] = 0;
  __syncthreads();

  int base = bid * CHUNK;
  int myd[EPT], mys[EPT];
#pragma unroll
  for (int i = 0; i < EPT; ++i) {
    int e = base + t + 256 * i;  // coalesced
    if (e < E) {
      myd[i] = dst[e];
      mys[i] = src[e];
      atomicAdd(&h[myd[i] >> BKSH], 1);
    } else myd[i] = -1;
  }
  __syncthreads();

  if (t < 64) {  // wave 0: exclusive scan of h[0..255], 4 per lane
    int i0 = 4 * t;
    int v0 = h[i0], v1 = h[i0 + 1], v2 = h[i0 + 2], v3 = h[i0 + 3];
    int s4 = v0 + v1 + v2 + v3, inc = s4;
#pragma unroll
    for (int off = 1; off < 64; off <<= 1) {
      int u = __shfl_up(inc, off, 64);
      if (t >= off) inc += u;
    }
    int ex = inc - s4;
    loff[i0] = ex; loff[i0 + 1] = ex + v0;
    loff[i0 + 2] = ex + v0 + v1; loff[i0 + 3] = ex + v0 + v1 + v2;
  }
  __syncthreads();

  if (t < NB) {
    if (h[t] > 0) gbase[t] = t * CAPE + atomicAdd(&cursor[t], h[t]);  // claim
  }
  __syncthreads();
  if (t < NBMAX) h[t] = 0;  // reuse as local cursor
  __syncthreads();

#pragma unroll
  for (int i = 0; i < EPT; ++i) {
    if (myd[i] >= 0) {
      int b = myd[i] >> BKSH;
      int p = atomicAdd(&h[b], 1);           // LDS int atomic: native, fast
      sbuf[loff[b] + p] = mys[i] | ((myd[i] & (BKN - 1)) << 17);  // src < 2^17
    }
  }
  __syncthreads();

  for (int b = w; b < NB; b += 4) {
    int c = h[b], lo = loff[b], go = gbase[b];
    for (int j = lane; j < c; j += 64)
      ebuf[go + j] = sbuf[lo + j];
  }
}

// One 512-thread block per 512-node bucket (196 blocks). Window read ONCE
// from global into registers; count -> block scan -> in-LDS node-sort ->
// coalesced flush. cnt[] doubles as scatter cursor (seeded with exclusive
// prefix), so the atomicAdd result IS the final sorted position.
__global__ __launch_bounds__(512) void sb_csr(const int* __restrict__ cursor,
                                              const int* __restrict__ ebuf,
                                              int* __restrict__ col,
                                              int2* __restrict__ rowse, int N) {
  __shared__ int sbuf[CAPE];   // 28672 B
  __shared__ int cnt[BKN];     //  2048 B
  __shared__ int wsum[8];      // total ~30.8 KB
  int b = blockIdx.x, t = threadIdx.x;
  int s = b * CAPE;
  int n = cursor[b];
  int e = s + n;

  // stage window into registers (static indices -> stays in VGPRs)
  int my[WPT];
#pragma unroll
  for (int i = 0; i < WPT; ++i) {
    int j = s + t + i * BKN;
    my[i] = (j < e) ? ebuf[j] : -1;  // entries < 2^26, -1 is a safe sentinel
  }

  cnt[t] = 0;
  __syncthreads();
#pragma unroll
  for (int i = 0; i < WPT; ++i)
    if (my[i] >= 0) atomicAdd(&cnt[(my[i] >> 17) & (BKN - 1)], 1);
  __syncthreads();

  // block exclusive scan over 512 (1 per thread, 8 waves)
  int v = cnt[t];
  int lane = t & 63, w = t >> 6;
  int inc = v;
#pragma unroll
  for (int o = 1; o < 64; o <<= 1) {
    int u = __shfl_up(inc, o, 64);
    if (lane >= o) inc += u;
  }
  if (lane == 63) wsum[w] = inc;
  __syncthreads();
  if (t < 8) {
    int s0 = wsum[t], incw = s0;
#pragma unroll
    for (int o = 1; o < 8; o <<= 1) {
      int u = __shfl_up(incw, o, 64);
      if (t >= o) incw += u;
    }
    wsum[t] = incw - s0;
  }
  __syncthreads();
  int ex = wsum[w] + inc - v;
  int node = (b << BKSH) + t;
  if (node < N) rowse[node] = make_int2(s + ex, v);
  __syncthreads();
  cnt[t] = ex;  // seed scatter cursor with exclusive prefix
  __syncthreads();

  // in-LDS node-sort: atomic result is the final position in the window
#pragma unroll
  for (int i = 0; i < WPT; ++i) {
    if (my[i] >= 0) {
      int nl = (my[i] >> 17) & (BKN - 1);
      int p = atomicAdd(&cnt[nl], 1);
      sbuf[p] = my[i] & 0x1FFFF;
    }
  }
  __syncthreads();

  // coalesced flush
  for (int j = t; j < n; j += BKN) col[s + j] = sbuf[j];
}

// Oct-per-node gather: 32 nodes/block (4 waves x 8 octs). Lane owns 8 dims of
// its oct's node across all edges -> no cross-lane reduce. Per 8 edges: one
// 32B col-line fetch per oct, then 8 independent z-row loads (8-deep ILP).
// Loop bound = wave-max degree (wave-uniform -> shfl-safe, R6); predicated-off
// lanes load z row 0 (L1-hot, harmless). Epilogue: all 64 lanes write
// (8 contiguous 256B rows per wave).
__global__ __launch_bounds__(256) void gather_oct(
    const unsigned short* __restrict__ zb,
    const int2* __restrict__ rowse,
    const int* __restrict__ col,
    const unsigned short* __restrict__ yb,
    float* __restrict__ out, int N) {
  int t = threadIdx.x;
  int lane = t & 63, w = t >> 6;
  int o = lane >> 3, d = lane & 7;
  int node = blockIdx.x * 32 + w * 8 + o;

  int2 se = rowse[min(node, N - 1)];  // 8 lanes/oct same addr -> broadcast
  int s0 = se.x;
  int c = (node < N) ? se.y : 0;
  int cm1 = max(c - 1, 0);

  // wave-max degree (uniform trip count for the shfl loop)
  int cmax = c;
#pragma unroll
  for (int m = 8; m <= 32; m <<= 1) cmax = max(cmax, __shfl_xor(cmax, m, 64));

  long long ro = (long long)node * 64 + d * 8;
  long long ros = (long long)min(node, N - 1) * 64 + d * 8;
  short8 yv8 = *(const short8*)&yb[ros];  // prefetch, independent of edge loop

  float a[8] = {0.f, 0.f, 0.f, 0.f, 0.f, 0.f, 0.f, 0.f};
  float b2[8] = {0.f, 0.f, 0.f, 0.f, 0.f, 0.f, 0.f, 0.f};
  for (int kb = 0; kb < cmax; kb += 8) {  // cmax wave-uniform
    int colv = col[s0 + min(kb + d, cm1)];  // 32B line per oct
#pragma unroll
    for (int j = 0; j < 8; ++j) {
      bool p = (kb + j) < c;  // oct-uniform predicate
      int cs = __shfl(colv, (lane & 56) | j, 64);  // all lanes active
      cs = p ? cs : 0;
      short8 v = *(const short8*)&zb[(long long)cs * 64 + d * 8];
      if (p) add8((j & 1) ? b2 : a, v);
    }
  }
#pragma unroll
  for (int k = 0; k < 8; ++k) a[k] += b2[k];

  if (node < N) {
    float inv = 1.0f / fmaxf((float)c, 1.0f);
    float yv[8];
    cvt8(yv, yv8);
    float4 r0, r1;
    r0.x = fmaxf(yv[0] + a[0] * inv, 0.f);
    r0.y = fmaxf(yv[1] + a[1] * inv, 0.f);
    r0.z = fmaxf(yv[2] + a[2] * inv, 0.f);
    r0.w = fmaxf(yv[3] + a[3] * inv, 0.f);
    r1.x = fmaxf(yv[4] + a[4] * inv, 0.f);
    r1.y = fmaxf(yv[5] + a[5] * inv, 0.f);
    r1.z = fmaxf(yv[6] + a[6] * inv, 0.f);
    r1.w = fmaxf(yv[7] + a[7] * inv, 0.f);
    *(float4*)&out[ro] = r0;
    *(float4*)&out[ro + 4] = r1;
  }
}

extern "C" void kernel_launch(void* const* d_in, const int* in_sizes, int n_in,
                              void* d_out, int out_size, void* d_ws, size_t ws_size,
                              hipStream_t stream) {
  const float* x      = (const float*)d_in[0];
  const int*   eidx   = (const int*)d_in[1];
  const float* Wself  = (const float*)d_in[2];
  const float* bself  = (const float*)d_in[3];
  const float* Wneigh = (const float*)d_in[4];
  float* out = (float*)d_out;

  const int N = in_sizes[0] / 64;
  const int E = in_sizes[1] / 2;
  const int* src = eidx;      // edge_index row 0
  const int* dst = eidx + E;  // edge_index row 1
  const int NB = (N + BKN - 1) / BKN;       // 196 buckets of 512 nodes
  const int SCB = (E + CHUNK - 1) / CHUNK;  // 306 scatter blocks

  // ws layout: yb bf16[N*64] | zb bf16[N*64] | cursor[256] | rowse int2[N]
  //            | ebuf[NB*CAPE] | col[NB*CAPE]   (~38 MB)
  unsigned short* yb = (unsigned short*)d_ws;
  unsigned short* zb = yb + (size_t)N * 64;
  int* cursor = (int*)(zb + (size_t)N * 64);
  int2* rowse = (int2*)(cursor + NBMAX);
  int* ebuf   = (int*)(rowse + N);
  int* col    = ebuf + (size_t)NB * CAPE;

  hipMemsetAsync(cursor, 0, NBMAX * sizeof(int), stream);

  const int GB = (N + 63) / 64;  // 1563 GEMM blocks (64 nodes each)
  k1_main<<<SCB + GB, 256, 0, stream>>>(x, Wself, bself, Wneigh, yb, zb,
                                        src, dst, cursor, ebuf, E, N, NB, SCB);
  sb_csr<<<NB, BKN, 0, stream>>>(cursor, ebuf, col, rowse, N);
  gather_oct<<<(N + 31) / 32, 256, 0, stream>>>(zb, rowse, col, yb, out, N);
}

// Round 13
// 156.453 us; speedup vs baseline: 1.1355x; 1.0016x over previous
//
#include <hip/hip_runtime.h>

// GCN layer: out = relu(x @ W_self^T + b_self + segment_mean(x[src], dst) @ W_neigh^T)
// N = 100000 nodes, D = 64, E = 1.25M edges.
//
// R3 structure: mean-then-matmul == matmul-then-mean (linearity).
// y = x@Ws^T + b and z = x@Wn^T computed FIRST (bf16 planes); gather averages
// z rows and finishes out = relu(y + mean).
// R4 lesson: per-edge scattered 4B global writes = 16x write amplification.
// R6 lesson: __shfl with divergent-exit loops is UB on gfx950 — all shfl loops
//   use wave-uniform trip counts with predication.
// R10/R12 lessons: cursor-claim storm, dispatch count, LDS contention, block
//   shape all falsified for k1's stubborn ~46 µs. R11: fat-block fusion caps
//   TLP for the latency-bound gather (keep many small blocks).
//
// R13: theory #7 for k1 — the GEMM role's 32 scalar 2-byte stores/thread
// (12.8M global_store_short) saturate the VMEM store queue (signature: all
// pipes idle, occupancy 33%, 1.3 TB/s). Fix: per-wave-private LDS transpose
// (sbuf region is unused by the GEMM role) -> 16B short8 stores (8/thread).
// Plus: gather prefetches the NEXT col line before the current 8 z-loads.
//
// Pipeline (memset + 3 kernels):
//   memset      : cursor[256] = 0.
//   k1_main     : blocks [0,SCB): LDS-staged radix scatter into 196 buckets
//                 of 512 dst-nodes (contiguous-run claim, full-line ebuf
//                 writes). Blocks [SCB,+GB): dual MFMA GEMM -> bf16 y,z with
//                 LDS-transposed wide stores.
//   sb_csr      : one 512-thread block per bucket: window in registers,
//                 in-LDS node-sort, coalesced flush. LDS *int* atomics only
//                 (fp32 LDS atomicAdd = CAS-loop disaster).
//   gather_oct  : 3125 blocks x 256 thr, 32 nodes/block, oct-per-node,
//                 8-deep z ILP + col-line prefetch.

#define BKSH 9                // log2(nodes per bucket)
#define BKN 512               // nodes per bucket
#define NBMAX 256             // >= NB = 196
#define CAPE 7168             // edge capacity per bucket (mean 6400, +9.6 sigma)
#define WPT (CAPE / BKN)      // window entries per thread in sb_csr = 14
#define CHUNK 4096            // edges per scatter block
#define EPT (CHUNK / 256)     // edges per thread in scatter = 16

typedef __attribute__((ext_vector_type(8))) short short8;
typedef __attribute__((ext_vector_type(4))) float floatx4;

// fp32 -> bf16 round-to-nearest-even, branch-free.
static __device__ inline unsigned short f2bf(float f) {
  union { float f; unsigned int u; } v;
  v.f = f;
  unsigned int r = v.u + 0x7FFFu + ((v.u >> 16) & 1u);
  return (unsigned short)(r >> 16);
}

static __device__ inline short8 pack8(float4 a, float4 b) {
  short8 s;
  s[0] = (short)f2bf(a.x); s[1] = (short)f2bf(a.y);
  s[2] = (short)f2bf(a.z); s[3] = (short)f2bf(a.w);
  s[4] = (short)f2bf(b.x); s[5] = (short)f2bf(b.y);
  s[6] = (short)f2bf(b.z); s[7] = (short)f2bf(b.w);
  return s;
}

// unpack 8 bf16 (4 dwords) and accumulate into 8 fp32.
static __device__ inline void add8(float* a, short8 sv) {
  union { short8 s; unsigned int u[4]; } c; c.s = sv;
#pragma unroll
  for (int i = 0; i < 4; ++i) {
    a[2 * i]     += __uint_as_float(c.u[i] << 16);
    a[2 * i + 1] += __uint_as_float(c.u[i] & 0xFFFF0000u);
  }
}

// unpack 8 bf16 into 8 fp32 (no accumulate).
static __device__ inline void cvt8(float* a, short8 sv) {
  union { short8 s; unsigned int u[4]; } c; c.s = sv;
#pragma unroll
  for (int i = 0; i < 4; ++i) {
    a[2 * i]     = __uint_as_float(c.u[i] << 16);
    a[2 * i + 1] = __uint_as_float(c.u[i] & 0xFFFF0000u);
  }
}

// Fused: edge radix-scatter (blocks < SCB) | dual-GEMM y,z from fp32 x.
__global__ __launch_bounds__(256) void k1_main(
    const float* __restrict__ x,
    const float* __restrict__ Wself, const float* __restrict__ bself,
    const float* __restrict__ Wneigh,
    unsigned short* __restrict__ yb, unsigned short* __restrict__ zb,
    const int* __restrict__ src, const int* __restrict__ dst,
    int* __restrict__ cursor, int* __restrict__ ebuf,
    int E, int N, int NB, int SCB) {
  __shared__ int h[NBMAX], loff[NBMAX], gbase[NBMAX];
  __shared__ int sbuf[CHUNK];
  int t = threadIdx.x;
  int bid = blockIdx.x;

  if (bid >= SCB) {
    // ---- GEMM role: y = x@Ws^T + b (bf16), z = x@Wn^T (bf16) ----
    // sbuf (16 KB) is unused by this role -> per-wave-private [16][64] bf16
    // transpose tiles (y then z), so global stores are 16B short8 instead of
    // 32 scalar 2B stores/thread (theory #7: store-queue saturation).
    int lane = t & 63;
    int w = t >> 6;
    int tb = (bid - SCB) * 64 + w * 16;
    int m = lane & 15, q = lane >> 4;
    unsigned short* lds  = (unsigned short*)sbuf;  // 8192 ushorts
    unsigned short* ylds = lds + w * 2048;         // [16 nodes][64 cols]
    unsigned short* zlds = ylds + 1024;

    long long rowA = (long long)min(tb + m, N - 1) * 64;
    short8 ax[2];
#pragma unroll
    for (int ks = 0; ks < 2; ++ks) {
      const float* xr = &x[rowA + ks * 32 + q * 8];
      ax[ks] = pack8(*(const float4*)xr, *(const float4*)(xr + 4));
    }

#pragma unroll
    for (int nt = 0; nt < 4; ++nt) {
      int ob = nt * 16;
      long long rowB = (long long)(ob + m) * 64;
      floatx4 accs = {0.f, 0.f, 0.f, 0.f};
      floatx4 accn = {0.f, 0.f, 0.f, 0.f};
#pragma unroll
      for (int ks = 0; ks < 2; ++ks) {
        const float* pw = &Wself[rowB + ks * 32 + q * 8];
        short8 bs = pack8(*(const float4*)pw, *(const float4*)(pw + 4));
        accs = __builtin_amdgcn_mfma_f32_16x16x32_bf16(ax[ks], bs, accs, 0, 0, 0);
        const float* pn = &Wneigh[rowB + ks * 32 + q * 8];
        short8 bn = pack8(*(const float4*)pn, *(const float4*)(pn + 4));
        accn = __builtin_amdgcn_mfma_f32_16x16x32_bf16(ax[ks], bn, accn, 0, 0, 0);
      }
      float bias = bself[ob + m];
#pragma unroll
      for (int r = 0; r < 4; ++r) {
        int nl = q * 4 + r;
        ylds[nl * 64 + ob + m] = f2bf(accs[r] + bias);  // 2B LDS write (cheap)
        zlds[nl * 64 + ob + m] = f2bf(accn[r]);
      }
    }
    // wave-private slice: no barrier needed; compiler orders ds ops via lgkmcnt
    if (tb + (lane >> 2) < N) {  // lane covers 32B of node tb + lane/4
      long long go = (long long)tb * 64 + lane * 16;
      *(short8*)&yb[go]     = *(short8*)&ylds[lane * 16];
      *(short8*)&yb[go + 8] = *(short8*)&ylds[lane * 16 + 8];
      *(short8*)&zb[go]     = *(short8*)&zlds[lane * 16];
      *(short8*)&zb[go + 8] = *(short8*)&zlds[lane * 16 + 8];
    }
    return;
  }

  // ---- scatter role ----
  int w = t >> 6, lane = t & 63;
  if (t < NBMAX) h[t] = 0;
  __syncthreads();

  int base = bid * CHUNK;
  int myd[EPT], mys[EPT];
#pragma unroll
  for (int i = 0; i < EPT; ++i) {
    int e = base + t + 256 * i;  // coalesced
    if (e < E) {
      myd[i] = dst[e];
      mys[i] = src[e];
      atomicAdd(&h[myd[i] >> BKSH], 1);
    } else myd[i] = -1;
  }
  __syncthreads();

  if (t < 64) {  // wave 0: exclusive scan of h[0..255], 4 per lane
    int i0 = 4 * t;
    int v0 = h[i0], v1 = h[i0 + 1], v2 = h[i0 + 2], v3 = h[i0 + 3];
    int s4 = v0 + v1 + v2 + v3, inc = s4;
#pragma unroll
    for (int off = 1; off < 64; off <<= 1) {
      int u = __shfl_up(inc, off, 64);
      if (t >= off) inc += u;
    }
    int ex = inc - s4;
    loff[i0] = ex; loff[i0 + 1] = ex + v0;
    loff[i0 + 2] = ex + v0 + v1; loff[i0 + 3] = ex + v0 + v1 + v2;
  }
  __syncthreads();

  if (t < NB) {
    if (h[t] > 0) gbase[t] = t * CAPE + atomicAdd(&cursor[t], h[t]);  // claim
  }
  __syncthreads();
  if (t < NBMAX) h[t] = 0;  // reuse as local cursor
  __syncthreads();

#pragma unroll
  for (int i = 0; i < EPT; ++i) {
    if (myd[i] >= 0) {
      int b = myd[i] >> BKSH;
      int p = atomicAdd(&h[b], 1);           // LDS int atomic: native, fast
      sbuf[loff[b] + p] = mys[i] | ((myd[i] & (BKN - 1)) << 17);  // src < 2^17
    }
  }
  __syncthreads();

  for (int b = w; b < NB; b += 4) {
    int c = h[b], lo = loff[b], go = gbase[b];
    for (int j = lane; j < c; j += 64)
      ebuf[go + j] = sbuf[lo + j];
  }
}

// One 512-thread block per 512-node bucket (196 blocks). Window read ONCE
// from global into registers; count -> block scan -> in-LDS node-sort ->
// coalesced flush. cnt[] doubles as scatter cursor (seeded with exclusive
// prefix), so the atomicAdd result IS the final sorted position.
__global__ __launch_bounds__(512) void sb_csr(const int* __restrict__ cursor,
                                              const int* __restrict__ ebuf,
                                              int* __restrict__ col,
                                              int2* __restrict__ rowse, int N) {
  __shared__ int sbuf[CAPE];   // 28672 B
  __shared__ int cnt[BKN];     //  2048 B
  __shared__ int wsum[8];      // total ~30.8 KB
  int b = blockIdx.x, t = threadIdx.x;
  int s = b * CAPE;
  int n = cursor[b];
  int e = s + n;

  // stage window into registers (static indices -> stays in VGPRs)
  int my[WPT];
#pragma unroll
  for (int i = 0; i < WPT; ++i) {
    int j = s + t + i * BKN;
    my[i] = (j < e) ? ebuf[j] : -1;  // entries < 2^26, -1 is a safe sentinel
  }

  cnt[t] = 0;
  __syncthreads();
#pragma unroll
  for (int i = 0; i < WPT; ++i)
    if (my[i] >= 0) atomicAdd(&cnt[(my[i] >> 17) & (BKN - 1)], 1);
  __syncthreads();

  // block exclusive scan over 512 (1 per thread, 8 waves)
  int v = cnt[t];
  int lane = t & 63, w = t >> 6;
  int inc = v;
#pragma unroll
  for (int o = 1; o < 64; o <<= 1) {
    int u = __shfl_up(inc, o, 64);
    if (lane >= o) inc += u;
  }
  if (lane == 63) wsum[w] = inc;
  __syncthreads();
  if (t < 8) {
    int s0 = wsum[t], incw = s0;
#pragma unroll
    for (int o = 1; o < 8; o <<= 1) {
      int u = __shfl_up(incw, o, 64);
      if (t >= o) incw += u;
    }
    wsum[t] = incw - s0;
  }
  __syncthreads();
  int ex = wsum[w] + inc - v;
  int node = (b << BKSH) + t;
  if (node < N) rowse[node] = make_int2(s + ex, v);
  __syncthreads();
  cnt[t] = ex;  // seed scatter cursor with exclusive prefix
  __syncthreads();

  // in-LDS node-sort: atomic result is the final position in the window
#pragma unroll
  for (int i = 0; i < WPT; ++i) {
    if (my[i] >= 0) {
      int nl = (my[i] >> 17) & (BKN - 1);
      int p = atomicAdd(&cnt[nl], 1);
      sbuf[p] = my[i] & 0x1FFFF;
    }
  }
  __syncthreads();

  // coalesced flush
  for (int j = t; j < n; j += BKN) col[s + j] = sbuf[j];
}

// Oct-per-node gather: 32 nodes/block (4 waves x 8 octs). Lane owns 8 dims of
// its oct's node across all edges -> no cross-lane reduce. Per 8 edges: one
// 32B col-line fetch per oct (PREFETCHED one iteration ahead), then 8
// independent z-row loads (8-deep ILP). Loop bound = wave-max degree
// (wave-uniform -> shfl-safe, R6); predicated-off lanes load z row 0 (L1-hot,
// harmless). Epilogue: all 64 lanes write (8 contiguous 256B rows per wave).
__global__ __launch_bounds__(256) void gather_oct(
    const unsigned short* __restrict__ zb,
    const int2* __restrict__ rowse,
    const int* __restrict__ col,
    const unsigned short* __restrict__ yb,
    float* __restrict__ out, int N) {
  int t = threadIdx.x;
  int lane = t & 63, w = t >> 6;
  int o = lane >> 3, d = lane & 7;
  int node = blockIdx.x * 32 + w * 8 + o;

  int2 se = rowse[min(node, N - 1)];  // 8 lanes/oct same addr -> broadcast
  int s0 = se.x;
  int c = (node < N) ? se.y : 0;
  int cm1 = max(c - 1, 0);

  // wave-max degree (uniform trip count for the shfl loop)
  int cmax = c;
#pragma unroll
  for (int m = 8; m <= 32; m <<= 1) cmax = max(cmax, __shfl_xor(cmax, m, 64));

  long long ro = (long long)node * 64 + d * 8;
  long long ros = (long long)min(node, N - 1) * 64 + d * 8;
  short8 yv8 = *(const short8*)&yb[ros];  // prefetch, independent of edge loop

  float a[8] = {0.f, 0.f, 0.f, 0.f, 0.f, 0.f, 0.f, 0.f};
  float b2[8] = {0.f, 0.f, 0.f, 0.f, 0.f, 0.f, 0.f, 0.f};
  int colv = col[s0 + min(d, cm1)];  // first 32B line per oct
  for (int kb = 0; kb < cmax; kb += 8) {  // cmax wave-uniform
    int colv_nx = 0;
    if (kb + 8 < cmax) colv_nx = col[s0 + min(kb + 8 + d, cm1)];  // prefetch
#pragma unroll
    for (int j = 0; j < 8; ++j) {
      bool p = (kb + j) < c;  // oct-uniform predicate
      int cs = __shfl(colv, (lane & 56) | j, 64);  // all lanes active
      cs = p ? cs : 0;
      short8 v = *(const short8*)&zb[(long long)cs * 64 + d * 8];
      if (p) add8((j & 1) ? b2 : a, v);
    }
    colv = colv_nx;
  }
#pragma unroll
  for (int k = 0; k < 8; ++k) a[k] += b2[k];

  if (node < N) {
    float inv = 1.0f / fmaxf((float)c, 1.0f);
    float yv[8];
    cvt8(yv, yv8);
    float4 r0, r1;
    r0.x = fmaxf(yv[0] + a[0] * inv, 0.f);
    r0.y = fmaxf(yv[1] + a[1] * inv, 0.f);
    r0.z = fmaxf(yv[2] + a[2] * inv, 0.f);
    r0.w = fmaxf(yv[3] + a[3] * inv, 0.f);
    r1.x = fmaxf(yv[4] + a[4] * inv, 0.f);
    r1.y = fmaxf(yv[5] + a[5] * inv, 0.f);
    r1.z = fmaxf(yv[6] + a[6] * inv, 0.f);
    r1.w = fmaxf(yv[7] + a[7] * inv, 0.f);
    *(float4*)&out[ro] = r0;
    *(float4*)&out[ro + 4] = r1;
  }
}

extern "C" void kernel_launch(void* const* d_in, const int* in_sizes, int n_in,
                              void* d_out, int out_size, void* d_ws, size_t ws_size,
                              hipStream_t stream) {
  const float* x      = (const float*)d_in[0];
  const int*   eidx   = (const int*)d_in[1];
  const float* Wself  = (const float*)d_in[2];
  const float* bself  = (const float*)d_in[3];
  const float* Wneigh = (const float*)d_in[4];
  float* out = (float*)d_out;

  const int N = in_sizes[0] / 64;
  const int E = in_sizes[1] / 2;
  const int* src = eidx;      // edge_index row 0
  const int* dst = eidx + E;  // edge_index row 1
  const int NB = (N + BKN - 1) / BKN;       // 196 buckets of 512 nodes
  const int SCB = (E + CHUNK - 1) / CHUNK;  // 306 scatter blocks

  // ws layout: yb bf16[N*64] | zb bf16[N*64] | cursor[256] | rowse int2[N]
  //            | ebuf[NB*CAPE] | col[NB*CAPE]   (~38 MB)
  unsigned short* yb = (unsigned short*)d_ws;
  unsigned short* zb = yb + (size_t)N * 64;
  int* cursor = (int*)(zb + (size_t)N * 64);
  int2* rowse = (int2*)(cursor + NBMAX);
  int* ebuf   = (int*)(rowse + N);
  int* col    = ebuf + (size_t)NB * CAPE;

  hipMemsetAsync(cursor, 0, NBMAX * sizeof(int), stream);

  const int GB = (N + 63) / 64;  // 1563 GEMM blocks (64 nodes each)
  k1_main<<<SCB + GB, 256, 0, stream>>>(x, Wself, bself, Wneigh, yb, zb,
                                        src, dst, cursor, ebuf, E, N, NB, SCB);
  sb_csr<<<NB, BKN, 0, stream>>>(cursor, ebuf, col, rowse, N);
  gather_oct<<<(N + 31) / 32, 256, 0, stream>>>(zb, rowse, col, yb, out, N);
}